// Round 1
// baseline (3581.430 us; speedup 1.0000x reference)
//
#include <hip/hip_runtime.h>
#include <hip/hip_bf16.h>

#define B_TOTAL 1024
#define T_TOTAL 1024

__device__ __forceinline__ float sigmoidf_(float z) {
    return 1.0f / (1.0f + __expf(-z));
}
__device__ __forceinline__ float tanhf_(float z) {
    // robust: exp overflow -> inf -> 2/inf=0 -> 1 ; exp underflow -> 0 -> -1
    return 1.0f - 2.0f / (__expf(2.0f * z) + 1.0f);
}

// One bidirectional-capable LSTM scan pass over all T for a batch tile.
// Thread = (b_local, gate_row j). Weight row lives in VGPRs; x/h tiles in LDS.
// dir = blockIdx.y (0 fwd, 1 bwd). Layers>1 read bf16 [T][B][DIN]; writes bf16 [T][B][2H].
template <int DIN, int H, int BT, bool LAYER1, bool STORE_ALL>
__global__ void lstm_scan(
    const float* __restrict__ x,                 // LAYER1 only: [B][T][8]
    const __hip_bfloat16* __restrict__ inbuf,    // layers>1:    [T][B][DIN]
    const float* __restrict__ wihf, const float* __restrict__ whhf,
    const float* __restrict__ bihf, const float* __restrict__ bhhf,
    const float* __restrict__ wihb, const float* __restrict__ whhb,
    const float* __restrict__ bihb, const float* __restrict__ bhhb,
    __hip_bfloat16* __restrict__ outbuf,         // STORE_ALL: [T][B][2H]
    float* __restrict__ lasth)                   // !STORE_ALL: [B][H]
{
    constexpr int G   = 4 * H;
    constexpr int NTH = BT * G;

    const int dir = blockIdx.y;
    const int tid = threadIdx.x;
    const int bl  = tid / G;      // batch within tile
    const int j   = tid % G;      // gate row
    const int b   = blockIdx.x * BT + bl;

    const float* w_ih = dir ? wihb : wihf;
    const float* w_hh = dir ? whhb : whhf;
    const float* b_ih = dir ? bihb : bihf;
    const float* b_hh = dir ? bhhb : bhhf;

    __shared__ float xs[BT][DIN];
    __shared__ float hs[BT][H];
    __shared__ float gs[BT][G];

    // weight row -> registers (once)
    float wih[DIN];
#pragma unroll
    for (int i = 0; i < DIN; ++i) wih[i] = w_ih[j * DIN + i];
    float whh[H];
#pragma unroll
    for (int k = 0; k < H; ++k) whh[k] = w_hh[j * H + k];
    const float bias = b_ih[j] + b_hh[j];

    float c = 0.0f;                    // valid for owner threads (j < H)
    if (j < H) hs[bl][j] = 0.0f;
    __syncthreads();

    for (int t = 0; t < T_TOTAL; ++t) {
        const int tt = dir ? (T_TOTAL - 1 - t) : t;

        // ---- stage input tile into LDS ----
        for (int idx = tid; idx < BT * DIN; idx += NTH) {
            const int ib = idx / DIN;
            const int ii = idx % DIN;
            const int gb = blockIdx.x * BT + ib;
            float v;
            if (LAYER1) {
                // in = concat(x[t], x[t-1] (zero at t=0)), DIN = 16
                if (ii < 8) {
                    v = x[(size_t)gb * (T_TOTAL * 8) + (size_t)tt * 8 + ii];
                } else {
                    v = (tt > 0)
                        ? x[(size_t)gb * (T_TOTAL * 8) + (size_t)(tt - 1) * 8 + (ii - 8)]
                        : 0.0f;
                }
            } else {
                v = __bfloat162float(inbuf[(size_t)tt * (B_TOTAL * DIN) + (size_t)gb * DIN + ii]);
            }
            xs[ib][ii] = v;
        }
        __syncthreads();

        // ---- gate dot product (weights in regs, x/h broadcast from LDS) ----
        float acc = bias;
#pragma unroll
        for (int i = 0; i < DIN; ++i) acc += wih[i] * xs[bl][i];
#pragma unroll
        for (int k = 0; k < H; ++k) acc += whh[k] * hs[bl][k];

        // distributed activation: i,f,o rows -> sigmoid ; g rows -> tanh
        float a;
        if (j < 2 * H || j >= 3 * H) a = sigmoidf_(acc);
        else                         a = tanhf_(acc);
        gs[bl][j] = a;
        __syncthreads();

        // ---- state update by owner threads ----
        if (j < H) {
            const float iv = gs[bl][j];
            const float fv = gs[bl][H + j];
            const float gv = gs[bl][2 * H + j];
            const float ov = gs[bl][3 * H + j];
            c = fv * c + iv * gv;
            const float h = ov * tanhf_(c);
            hs[bl][j] = h;
            if (STORE_ALL) {
                outbuf[(size_t)tt * (B_TOTAL * 2 * H) + (size_t)b * (2 * H) + dir * H + j] =
                    __float2bfloat16(h);
            } else {
                if (tt == T_TOTAL - 1) lasth[b * H + j] = h;
            }
        }
        __syncthreads();
    }
}

// L4 backward is only needed at t = T-1: a single step from zero state.
// Then fuse the FC + sigmoid.
__global__ void final_kernel(const __hip_bfloat16* __restrict__ l3out, // [T][B][20]
                             const float* __restrict__ hf4,            // [B][10]
                             const float* __restrict__ w_ih,           // w4b_ih [40][20]
                             const float* __restrict__ b_ih,
                             const float* __restrict__ b_hh,
                             const float* __restrict__ fc_w,           // [20]
                             const float* __restrict__ fc_b,           // [1]
                             float* __restrict__ out)                  // [B]
{
    const int b = blockIdx.x * blockDim.x + threadIdx.x;
    if (b >= B_TOTAL) return;

    float in4[20];
    const __hip_bfloat16* p = l3out + (size_t)(T_TOTAL - 1) * (B_TOTAL * 20) + (size_t)b * 20;
#pragma unroll
    for (int i = 0; i < 20; ++i) in4[i] = __bfloat162float(p[i]);

    float z = fc_b[0];
#pragma unroll
    for (int k = 0; k < 10; ++k) z += fc_w[k] * hf4[b * 10 + k];

#pragma unroll
    for (int k = 0; k < 10; ++k) {
        float gi = b_ih[k]      + b_hh[k];
        float gg = b_ih[20 + k] + b_hh[20 + k];
        float go = b_ih[30 + k] + b_hh[30 + k];
#pragma unroll
        for (int i = 0; i < 20; ++i) {
            const float xi = in4[i];
            gi += w_ih[k * 20 + i]        * xi;
            gg += w_ih[(20 + k) * 20 + i] * xi;
            go += w_ih[(30 + k) * 20 + i] * xi;
        }
        // c_prev = 0: c = sigmoid(i)*tanh(g) ; h = sigmoid(o)*tanh(c)
        const float cc = sigmoidf_(gi) * tanhf_(gg);
        const float hb = sigmoidf_(go) * tanhf_(cc);
        z += fc_w[10 + k] * hb;
    }
    out[b] = sigmoidf_(z);
}

extern "C" void kernel_launch(void* const* d_in, const int* in_sizes, int n_in,
                              void* d_out, int out_size, void* d_ws, size_t ws_size,
                              hipStream_t stream) {
    const float* x = (const float*)d_in[0];
    auto W = [&](int li, int dr, int k) -> const float* {
        return (const float*)d_in[1 + (li - 1) * 8 + dr * 4 + k];
    };
    const float* fc_w = (const float*)d_in[33];
    const float* fc_b = (const float*)d_in[34];
    float* out = (float*)d_out;

    // workspace: buf0 [T][B][40] bf16 (80MB), buf1 [T][B][40] bf16 (80MB), hf4 [B][10] f32
    __hip_bfloat16* buf0 = (__hip_bfloat16*)d_ws;
    __hip_bfloat16* buf1 = buf0 + (size_t)T_TOTAL * B_TOTAL * 40;
    float* hf4 = (float*)(buf1 + (size_t)T_TOTAL * B_TOTAL * 40);

    constexpr int BT = 4;
    const int nblk = B_TOTAL / BT; // 256 per direction

    // Layer 1: DIN=16, H=20 -> out buf0 [T][B][40]
    lstm_scan<16, 20, BT, true, true><<<dim3(nblk, 2, 1), BT * 80, 0, stream>>>(
        x, nullptr,
        W(1,0,0), W(1,0,1), W(1,0,2), W(1,0,3),
        W(1,1,0), W(1,1,1), W(1,1,2), W(1,1,3),
        buf0, nullptr);

    // Layer 2: DIN=40, H=20 -> out buf1 [T][B][40]
    lstm_scan<40, 20, BT, false, true><<<dim3(nblk, 2, 1), BT * 80, 0, stream>>>(
        nullptr, buf0,
        W(2,0,0), W(2,0,1), W(2,0,2), W(2,0,3),
        W(2,1,0), W(2,1,1), W(2,1,2), W(2,1,3),
        buf1, nullptr);

    // Layer 3: DIN=40, H=10 -> out buf0 [T][B][20]
    lstm_scan<40, 10, BT, false, true><<<dim3(nblk, 2, 1), BT * 40, 0, stream>>>(
        nullptr, buf1,
        W(3,0,0), W(3,0,1), W(3,0,2), W(3,0,3),
        W(3,1,0), W(3,1,1), W(3,1,2), W(3,1,3),
        buf0, nullptr);

    // Layer 4 forward only: DIN=20, H=10 -> lasth hf4 [B][10]
    lstm_scan<20, 10, BT, false, false><<<dim3(nblk, 1, 1), BT * 40, 0, stream>>>(
        nullptr, buf0,
        W(4,0,0), W(4,0,1), W(4,0,2), W(4,0,3),
        W(4,0,0), W(4,0,1), W(4,0,2), W(4,0,3), // dir=1 unused
        nullptr, hf4);

    // L4 backward single step + FC + sigmoid
    final_kernel<<<dim3(4, 1, 1), 256, 0, stream>>>(
        buf0, hf4, W(4,1,0), W(4,1,2), W(4,1,3), fc_w, fc_b, out);
}

// Round 2
// 2230.513 us; speedup vs baseline: 1.6057x; 1.6057x over previous
//
#include <hip/hip_runtime.h>
#include <hip/hip_bf16.h>
#include <hip/hip_fp16.h>
#include <stdint.h>

#define B_TOTAL 1024
#define T_TOTAL 1024
#define LOG2E 1.44269504088896f

typedef _Float16 f16x2 __attribute__((ext_vector_type(2)));

#if __has_builtin(__builtin_amdgcn_fdot2)
#define USE_DOT2 1
#else
#define USE_DOT2 0
#endif

__device__ __forceinline__ float dot2acc(uint32_t xw, f16x2 w, float acc) {
#if USE_DOT2
    return __builtin_amdgcn_fdot2(__builtin_bit_cast(f16x2, xw), w, acc, false);
#else
    f16x2 xv = __builtin_bit_cast(f16x2, xw);
    acc += (float)xv.x * (float)w.x;
    acc += (float)xv.y * (float)w.y;
    return acc;
#endif
}

__device__ __forceinline__ float fast_sig_aff(float z, float mneg, float sc, float off) {
    // a = sc * sigmoid(m*z) + off  computed branch-free:
    // sigmoid(m z) = 1/(1+2^(mneg*z)) with mneg = -m*log2(e)
    float e = __builtin_amdgcn_exp2f(mneg * z);
    float r = __builtin_amdgcn_rcpf(1.0f + e);
    return __builtin_fmaf(sc, r, off);
}

__device__ __forceinline__ float fast_tanh(float z) {
    // tanh(z) = 1 - 2/(1+exp(2z))
    float e = __builtin_amdgcn_exp2f(z * (2.0f * LOG2E));
    float r = __builtin_amdgcn_rcpf(1.0f + e);
    return __builtin_fmaf(-2.0f, r, 1.0f);
}

// Thread = (batch_local bl, gate_row j). Weights in VGPRs (f16 pairs).
// x loaded per-thread direct from global (pipelined, L1-broadcast); h via LDS f16.
// 2 barriers per step. dir = blockIdx.y.
template <int DIN, int H, int BT, bool LAYER1, bool STORE_ALL>
__global__ void lstm_scan(
    const float* __restrict__ x,              // LAYER1: [B][T][8] f32
    const __half* __restrict__ inbuf,         // layers>1: [T][B][DIN] f16
    const float* __restrict__ wihf, const float* __restrict__ whhf,
    const float* __restrict__ bihf, const float* __restrict__ bhhf,
    const float* __restrict__ wihb, const float* __restrict__ whhb,
    const float* __restrict__ bihb, const float* __restrict__ bhhb,
    __half* __restrict__ outbuf,              // STORE_ALL: [T][B][2H] f16
    float* __restrict__ lasth)                // !STORE_ALL: [B][H] f32
{
    constexpr int G  = 4 * H;
    constexpr int ND = DIN / 2;               // f16 dwords per input row
    constexpr int NH = H / 2;                 // f16 dwords per h row
    constexpr int HS = (H == 20) ? 24 : 16;   // padded h row (halves), 16B-aligned rows

    const int dir = blockIdx.y;
    const int tid = threadIdx.x;
    const int bl  = tid / G;
    const int j   = tid - bl * G;
    const int b   = blockIdx.x * BT + bl;

    const float* w_ih = dir ? wihb : wihf;
    const float* w_hh = dir ? whhb : whhf;
    const float* b_ih = dir ? bihb : bihf;
    const float* b_hh = dir ? bhhb : bhhf;

    __shared__ __half hsm[BT][HS];
    __shared__ float  gsm[BT][G];

    // ---- weights -> registers (once) ----
    f16x2 wih2[LAYER1 ? 1 : ND];
    float wih1[LAYER1 ? 16 : 1];
    if constexpr (LAYER1) {
#pragma unroll
        for (int i = 0; i < 16; ++i) wih1[i] = w_ih[j * 16 + i];
    } else {
#pragma unroll
        for (int d = 0; d < ND; ++d) {
            f16x2 t;
            t.x = (_Float16)w_ih[j * DIN + 2 * d];
            t.y = (_Float16)w_ih[j * DIN + 2 * d + 1];
            wih2[d] = t;
        }
    }
    f16x2 whh2[NH];
#pragma unroll
    for (int k = 0; k < NH; ++k) {
        f16x2 t;
        t.x = (_Float16)w_hh[j * H + 2 * k];
        t.y = (_Float16)w_hh[j * H + 2 * k + 1];
        whh2[k] = t;
    }
    const float bias = b_ih[j] + b_hh[j];

    // branch-free activation constants (i,f,o: sigmoid; g: tanh = 2*sig(2z)-1)
    const bool  isg  = (j >= 2 * H) && (j < 3 * H);
    const float mneg = isg ? (-2.0f * LOG2E) : (-LOG2E);
    const float sc   = isg ? 2.0f : 1.0f;
    const float off  = isg ? -1.0f : 0.0f;

    const int tstep = dir ? -1 : 1;
    int tt = dir ? (T_TOTAL - 1) : 0;

    // ---- per-thread input pipeline ----
    const float* xrow = LAYER1 ? (x + (size_t)b * T_TOTAL * 8) : nullptr;
    float xa[LAYER1 ? 8 : 1], xb[LAYER1 ? 8 : 1];
    uint32_t xc[LAYER1 ? 1 : ND];
    const uint32_t* ip = nullptr;
    int ipstep = 0;

    if constexpr (LAYER1) {
        if (dir) {
            const float* p = xrow + (size_t)(T_TOTAL - 1) * 8;
#pragma unroll
            for (int i = 0; i < 8; ++i) xa[i] = p[i];
            const float* q = xrow + (size_t)(T_TOTAL - 2) * 8;
#pragma unroll
            for (int i = 0; i < 8; ++i) xb[i] = q[i];
        } else {
            const float* p = xrow;
#pragma unroll
            for (int i = 0; i < 8; ++i) xa[i] = p[i];
#pragma unroll
            for (int i = 0; i < 8; ++i) xb[i] = 0.0f;
        }
    } else {
        ipstep = tstep * (B_TOTAL * ND);
        ip = (const uint32_t*)inbuf + (size_t)tt * (B_TOTAL * ND) + (size_t)b * ND;
#pragma unroll
        for (int d = 0; d < ND; ++d) xc[d] = ip[d];
        ip += ipstep;
    }

    // output pointer (owners only use it; increment uniformly)
    __half* op = nullptr;
    int opstep = 0;
    if constexpr (STORE_ALL) {
        op = outbuf + (size_t)tt * (B_TOTAL * 2 * H) + (size_t)b * (2 * H) + dir * H + j;
        opstep = tstep * (B_TOTAL * 2 * H);
    }

    float c = 0.0f;
    if (j < H) hsm[bl][j] = __float2half(0.0f);
    __syncthreads();

    for (int t = 0; t < T_TOTAL; ++t) {
        // ---- x-part of gates (uses current regs) ----
        float acc[4] = {bias, 0.0f, 0.0f, 0.0f};
        if constexpr (LAYER1) {
#pragma unroll
            for (int i = 0; i < 8; ++i) acc[i & 3] = __builtin_fmaf(wih1[i], xa[i], acc[i & 3]);
#pragma unroll
            for (int i = 0; i < 8; ++i) acc[i & 3] = __builtin_fmaf(wih1[8 + i], xb[i], acc[i & 3]);
        } else {
#pragma unroll
            for (int d = 0; d < ND; ++d) acc[d & 3] = dot2acc(xc[d], wih2[d], acc[d & 3]);
        }

        // ---- issue next step's input loads (latency hidden over rest of step) ----
        if constexpr (LAYER1) {
            const int lr = dir ? (tt - 2) : (tt + 1);
            if (dir) {
#pragma unroll
                for (int i = 0; i < 8; ++i) xa[i] = xb[i];
                if (lr >= 0) {
                    const float* p = xrow + (size_t)lr * 8;
#pragma unroll
                    for (int i = 0; i < 8; ++i) xb[i] = p[i];
                } else {
#pragma unroll
                    for (int i = 0; i < 8; ++i) xb[i] = 0.0f;
                }
            } else {
#pragma unroll
                for (int i = 0; i < 8; ++i) xb[i] = xa[i];
                if (lr < T_TOTAL) {
                    const float* p = xrow + (size_t)lr * 8;
#pragma unroll
                    for (int i = 0; i < 8; ++i) xa[i] = p[i];
                }
            }
        } else {
            if (t + 1 < T_TOTAL) {
#pragma unroll
                for (int d = 0; d < ND; ++d) xc[d] = ip[d];
                ip += ipstep;
            }
        }

        // ---- h-part of gates (LDS f16, vectorized reads) ----
        {
            const uint32_t* hp = (const uint32_t*)&hsm[bl][0];
            uint32_t hreg[NH];
#pragma unroll
            for (int k = 0; k < NH; ++k) hreg[k] = hp[k];
#pragma unroll
            for (int k = 0; k < NH; ++k) acc[k & 3] = dot2acc(hreg[k], whh2[k], acc[k & 3]);
        }
        const float z = (acc[0] + acc[1]) + (acc[2] + acc[3]);
        gsm[bl][j] = fast_sig_aff(z, mneg, sc, off);
        __syncthreads();

        // ---- state update by owner threads ----
        if (j < H) {
            const float iv = gsm[bl][j];
            const float fv = gsm[bl][H + j];
            const float gv = gsm[bl][2 * H + j];
            const float ov = gsm[bl][3 * H + j];
            c = __builtin_fmaf(fv, c, iv * gv);
            const float h = ov * fast_tanh(c);
            hsm[bl][j] = __float2half(h);
            if constexpr (STORE_ALL) {
                *op = __float2half(h);
            } else {
                if (t == T_TOTAL - 1) lasth[b * H + j] = h;
            }
        }
        if constexpr (STORE_ALL) op += opstep;
        __syncthreads();
        tt += tstep;
    }
}

// L4 backward needed only at t=T-1 (single step from zero state) + FC + sigmoid.
__global__ void final_kernel(const __half* __restrict__ l3out,  // [T][B][20] f16
                             const float* __restrict__ hf4,     // [B][10]
                             const float* __restrict__ w_ih,    // w4b_ih [40][20]
                             const float* __restrict__ b_ih,
                             const float* __restrict__ b_hh,
                             const float* __restrict__ fc_w,    // [20]
                             const float* __restrict__ fc_b,
                             float* __restrict__ out)           // [B]
{
    const int b = blockIdx.x * blockDim.x + threadIdx.x;
    if (b >= B_TOTAL) return;

    float in4[20];
    const __half* p = l3out + (size_t)(T_TOTAL - 1) * (B_TOTAL * 20) + (size_t)b * 20;
#pragma unroll
    for (int i = 0; i < 20; ++i) in4[i] = __half2float(p[i]);

    float z = fc_b[0];
#pragma unroll
    for (int k = 0; k < 10; ++k) z += fc_w[k] * hf4[b * 10 + k];

#pragma unroll
    for (int k = 0; k < 10; ++k) {
        float gi = b_ih[k]      + b_hh[k];
        float gg = b_ih[20 + k] + b_hh[20 + k];
        float go = b_ih[30 + k] + b_hh[30 + k];
#pragma unroll
        for (int i = 0; i < 20; ++i) {
            const float xi = in4[i];
            gi += w_ih[k * 20 + i]        * xi;
            gg += w_ih[(20 + k) * 20 + i] * xi;
            go += w_ih[(30 + k) * 20 + i] * xi;
        }
        const float cc = fast_sig_aff(gi, -LOG2E, 1.0f, 0.0f) * fast_tanh(gg);
        const float hb = fast_sig_aff(go, -LOG2E, 1.0f, 0.0f) * fast_tanh(cc);
        z += fc_w[10 + k] * hb;
    }
    out[b] = fast_sig_aff(z, -LOG2E, 1.0f, 0.0f);
}

extern "C" void kernel_launch(void* const* d_in, const int* in_sizes, int n_in,
                              void* d_out, int out_size, void* d_ws, size_t ws_size,
                              hipStream_t stream) {
    const float* x = (const float*)d_in[0];
    auto W = [&](int li, int dr, int k) -> const float* {
        return (const float*)d_in[1 + (li - 1) * 8 + dr * 4 + k];
    };
    const float* fc_w = (const float*)d_in[33];
    const float* fc_b = (const float*)d_in[34];
    float* out = (float*)d_out;

    // ws: buf0 [T][B][40] f16 (80MB), buf1 [T][B][40] f16 (80MB), hf4 [B][10] f32
    __half* buf0 = (__half*)d_ws;
    __half* buf1 = buf0 + (size_t)T_TOTAL * B_TOTAL * 40;
    float* hf4 = (float*)(buf1 + (size_t)T_TOTAL * B_TOTAL * 40);

    // Layer 1: DIN=16 (x + lag), H=20 -> buf0 [T][B][40]
    lstm_scan<16, 20, 4, true, true><<<dim3(256, 2, 1), 320, 0, stream>>>(
        x, nullptr,
        W(1,0,0), W(1,0,1), W(1,0,2), W(1,0,3),
        W(1,1,0), W(1,1,1), W(1,1,2), W(1,1,3),
        buf0, nullptr);

    // Layer 2: DIN=40, H=20 -> buf1 [T][B][40]
    lstm_scan<40, 20, 4, false, true><<<dim3(256, 2, 1), 320, 0, stream>>>(
        nullptr, buf0,
        W(2,0,0), W(2,0,1), W(2,0,2), W(2,0,3),
        W(2,1,0), W(2,1,1), W(2,1,2), W(2,1,3),
        buf1, nullptr);

    // Layer 3: DIN=40, H=10 -> buf0 [T][B][20]
    lstm_scan<40, 10, 4, false, true><<<dim3(256, 2, 1), 160, 0, stream>>>(
        nullptr, buf1,
        W(3,0,0), W(3,0,1), W(3,0,2), W(3,0,3),
        W(3,1,0), W(3,1,1), W(3,1,2), W(3,1,3),
        buf0, nullptr);

    // Layer 4 forward only: DIN=20, H=10 -> hf4 [B][10]
    lstm_scan<20, 10, 4, false, false><<<dim3(256, 1, 1), 160, 0, stream>>>(
        nullptr, buf0,
        W(4,0,0), W(4,0,1), W(4,0,2), W(4,0,3),
        W(4,0,0), W(4,0,1), W(4,0,2), W(4,0,3), // dir=1 never launched
        nullptr, hf4);

    // L4 backward single step + FC + sigmoid
    final_kernel<<<dim3(4, 1, 1), 256, 0, stream>>>(
        buf0, hf4, W(4,1,0), W(4,1,2), W(4,1,3), fc_w, fc_b, out);
}

// Round 3
// 1758.806 us; speedup vs baseline: 2.0363x; 1.2682x over previous
//
#include <hip/hip_runtime.h>
#include <hip/hip_fp16.h>
#include <stdint.h>

#define B_TOTAL 1024
#define T_TOTAL 1024
#define LOG2E 1.44269504088896f

typedef _Float16 f16x2 __attribute__((ext_vector_type(2)));

__device__ __forceinline__ float dot2acc(uint32_t xw, f16x2 w, float acc) {
#if __has_builtin(__builtin_amdgcn_fdot2)
    return __builtin_amdgcn_fdot2(__builtin_bit_cast(f16x2, xw), w, acc, false);
#else
    f16x2 xv = __builtin_bit_cast(f16x2, xw);
    return acc + (float)xv.x * (float)w.x + (float)xv.y * (float)w.y;
#endif
}

__device__ __forceinline__ uint32_t packf2(float a, float b) {
    f16x2 t;
    t.x = (_Float16)a;
    t.y = (_Float16)b;
    return __builtin_bit_cast(uint32_t, t);
}

__device__ __forceinline__ float sigm_(float z) {
    float e = __builtin_amdgcn_exp2f(-LOG2E * z);
    return __builtin_amdgcn_rcpf(1.0f + e);
}
__device__ __forceinline__ float tanh_(float z) {
    float e = __builtin_amdgcn_exp2f((2.0f * LOG2E) * z);
    float r = __builtin_amdgcn_rcpf(1.0f + e);
    return __builtin_fmaf(-2.0f, r, 1.0f);
}

__device__ __forceinline__ void wavebar() {
#if __has_builtin(__builtin_amdgcn_wave_barrier)
    __builtin_amdgcn_wave_barrier();
#endif
}

// Lane = (batch-group g, hidden unit j). Each lane computes ALL 4 gates for
// unit j: no gate exchange, no __syncthreads. Groups fit in ONE wave
// (3x H=20 or 6x H=10), so the h broadcast is wave-lockstep LDS.
// Weights live in VGPRs (f16x2). Input prefetched 4 deep (quad buffer).
template <int DIN, int H, bool LAYER1, bool STORE_ALL>
__global__ void __launch_bounds__(64) lstm_scan(
    const float* __restrict__ x,              // LAYER1: [B][T][8] f32
    const __half* __restrict__ inbuf,         // layers>1: [T][B][DIN] f16
    const float* __restrict__ wihf, const float* __restrict__ whhf,
    const float* __restrict__ bihf, const float* __restrict__ bhhf,
    const float* __restrict__ wihb, const float* __restrict__ whhb,
    const float* __restrict__ bihb, const float* __restrict__ bhhb,
    __half* __restrict__ outbuf,              // STORE_ALL: [T][B][2H] f16
    float* __restrict__ lasth)                // !STORE_ALL: [B][H] f32
{
    constexpr int GPW   = 64 / H;     // batch groups per wave (3 or 6)
    constexpr int ND    = DIN / 2;    // input dwords (f16 pairs)
    constexpr int NH    = H / 2;      // h dwords
    constexpr int HS_DW = (H == 20) ? 12 : 8;  // padded LDS row (16B aligned)

    const int dir  = blockIdx.y;
    const int lane = threadIdx.x;
    const int g    = lane / H;
    const int j    = lane - g * H;
    const int b    = blockIdx.x * GPW + g;
    const bool valid = (g < GPW) && (b < B_TOTAL);
    const int bs   = valid ? b : (B_TOTAL - 1);

    const float* w_ih = dir ? wihb : wihf;
    const float* w_hh = dir ? whhb : whhf;
    const float* b_ih = dir ? bihb : bihf;
    const float* b_hh = dir ? bhhb : bhhf;

    __shared__ uint32_t hsm[GPW + 1][HS_DW];

    // ---- weights for all 4 gates of unit j -> registers (f16 pairs) ----
    f16x2 wih2[4][ND];
    f16x2 whh2[4][NH];
    float bias[4];
#pragma unroll
    for (int q = 0; q < 4; ++q) {
        const int r = q * H + j;
#pragma unroll
        for (int d = 0; d < ND; ++d) {
            f16x2 t;
            t.x = (_Float16)w_ih[r * DIN + 2 * d];
            t.y = (_Float16)w_ih[r * DIN + 2 * d + 1];
            wih2[q][d] = t;
        }
#pragma unroll
        for (int k = 0; k < NH; ++k) {
            f16x2 t;
            t.x = (_Float16)w_hh[r * H + 2 * k];
            t.y = (_Float16)w_hh[r * H + 2 * k + 1];
            whh2[q][k] = t;
        }
        bias[q] = b_ih[r] + b_hh[r];
    }

    const int tstep = dir ? -1 : 1;
    int tt = dir ? (T_TOTAL - 1) : 0;

    // output pointer (store guarded by `valid`)
    __half* op = nullptr;
    ptrdiff_t opstep = 0;
    if constexpr (STORE_ALL) {
        op = outbuf + (size_t)tt * (B_TOTAL * 2 * H) + (size_t)bs * (2 * H) + dir * H + j;
        opstep = (ptrdiff_t)tstep * (B_TOTAL * 2 * H);
    }

    float c = 0.0f;
    ((__half*)&hsm[g][0])[j] = __float2half(0.0f);
    wavebar();

    int tcnt = 0;

    // shared tail: h-dots, activations, state update, h broadcast, store
    auto tail = [&](const uint32_t* hd, float a0, float a1, float a2, float a3) {
#pragma unroll
        for (int k = 0; k < NH; ++k) {
            a0 = dot2acc(hd[k], whh2[0][k], a0);
            a1 = dot2acc(hd[k], whh2[1][k], a1);
            a2 = dot2acc(hd[k], whh2[2][k], a2);
            a3 = dot2acc(hd[k], whh2[3][k], a3);
        }
        const float iv = sigm_(a0);
        const float fv = sigm_(a1);
        const float gv = tanh_(a2);
        const float ov = sigm_(a3);
        c = __builtin_fmaf(fv, c, iv * gv);
        const float h = ov * tanh_(c);
        ((__half*)&hsm[g][0])[j] = __float2half(h);
        wavebar();
        if constexpr (STORE_ALL) {
            if (valid) *op = __float2half(h);
            op += opstep;
        } else {
            if (valid && tcnt == T_TOTAL - 1) lasth[b * H + j] = h;
        }
        ++tcnt;
        tt += tstep;
    };

    if constexpr (LAYER1) {
        const float* xrow = x + (size_t)bs * (T_TOTAL * 8);
        uint32_t xcur[4], xlag[4];
        {
            const float4* p = (const float4*)(xrow + (size_t)tt * 8);
            float4 u0 = p[0], u1 = p[1];
            xcur[0] = packf2(u0.x, u0.y); xcur[1] = packf2(u0.z, u0.w);
            xcur[2] = packf2(u1.x, u1.y); xcur[3] = packf2(u1.z, u1.w);
            if (dir) {
                const float4* q = (const float4*)(xrow + (size_t)(tt - 1) * 8);
                float4 v0 = q[0], v1 = q[1];
                xlag[0] = packf2(v0.x, v0.y); xlag[1] = packf2(v0.z, v0.w);
                xlag[2] = packf2(v1.x, v1.y); xlag[3] = packf2(v1.z, v1.w);
            } else {
#pragma unroll
                for (int d = 0; d < 4; ++d) xlag[d] = 0u;
            }
        }

        for (int t = 0; t < T_TOTAL; ++t) {
            uint32_t hd[NH];
#pragma unroll
            for (int k = 0; k < NH; ++k) hd[k] = hsm[g][k];

            float a0 = bias[0], a1 = bias[1], a2 = bias[2], a3 = bias[3];
#pragma unroll
            for (int d = 0; d < 4; ++d) {
                a0 = dot2acc(xcur[d], wih2[0][d], a0);
                a1 = dot2acc(xcur[d], wih2[1][d], a1);
                a2 = dot2acc(xcur[d], wih2[2][d], a2);
                a3 = dot2acc(xcur[d], wih2[3][d], a3);
            }
#pragma unroll
            for (int d = 0; d < 4; ++d) {
                a0 = dot2acc(xlag[d], wih2[0][4 + d], a0);
                a1 = dot2acc(xlag[d], wih2[1][4 + d], a1);
                a2 = dot2acc(xlag[d], wih2[2][4 + d], a2);
                a3 = dot2acc(xlag[d], wih2[3][4 + d], a3);
            }

            // prefetch next step's fresh row
            const int li = dir ? (tt - 2) : (tt + 1);
            const bool ld = (li >= 0) && (li < T_TOTAL);
            float4 n0 = {0, 0, 0, 0}, n1 = {0, 0, 0, 0};
            if (ld) {
                const float4* p = (const float4*)(xrow + (size_t)li * 8);
                n0 = p[0];
                n1 = p[1];
            }

            tail(hd, a0, a1, a2, a3);

            uint32_t np[4] = {packf2(n0.x, n0.y), packf2(n0.z, n0.w),
                              packf2(n1.x, n1.y), packf2(n1.z, n1.w)};
            if (dir == 0) {
#pragma unroll
                for (int d = 0; d < 4; ++d) { xlag[d] = xcur[d]; xcur[d] = np[d]; }
            } else {
#pragma unroll
                for (int d = 0; d < 4; ++d) {
                    xcur[d] = xlag[d];
                    xlag[d] = ld ? np[d] : 0u;
                }
            }
        }
    } else {
        const ptrdiff_t ipstep = (ptrdiff_t)tstep * (B_TOTAL * ND);
        const uint32_t* ip = (const uint32_t*)inbuf + (size_t)tt * (B_TOTAL * ND) + (size_t)bs * ND;

        uint32_t xb[4][ND];
#pragma unroll
        for (int s = 0; s < 3; ++s) {
#pragma unroll
            for (int d = 0; d < ND; ++d) xb[s][d] = ip[d];
            ip += ipstep;
        }

        auto step = [&](const uint32_t* xc, uint32_t* xn, bool pf) {
            uint32_t hd[NH];
#pragma unroll
            for (int k = 0; k < NH; ++k) hd[k] = hsm[g][k];

            float a0 = bias[0], a1 = bias[1], a2 = bias[2], a3 = bias[3];
#pragma unroll
            for (int d = 0; d < ND; ++d) {
                a0 = dot2acc(xc[d], wih2[0][d], a0);
                a1 = dot2acc(xc[d], wih2[1][d], a1);
                a2 = dot2acc(xc[d], wih2[2][d], a2);
                a3 = dot2acc(xc[d], wih2[3][d], a3);
            }
            if (pf) {
#pragma unroll
                for (int d = 0; d < ND; ++d) xn[d] = ip[d];
                ip += ipstep;
            }
            tail(hd, a0, a1, a2, a3);
        };

        for (int t = 0; t < T_TOTAL; t += 4) {
            step(xb[0], xb[3], t + 3 < T_TOTAL);
            step(xb[1], xb[0], t + 4 < T_TOTAL);
            step(xb[2], xb[1], t + 5 < T_TOTAL);
            step(xb[3], xb[2], t + 6 < T_TOTAL);
        }
    }
}

// L4 backward needed only at t=T-1 (single step from zero state) + FC + sigmoid.
__global__ void final_kernel(const __half* __restrict__ l3out,  // [T][B][20] f16
                             const float* __restrict__ hf4,     // [B][10]
                             const float* __restrict__ w_ih,    // w4b_ih [40][20]
                             const float* __restrict__ b_ih,
                             const float* __restrict__ b_hh,
                             const float* __restrict__ fc_w,    // [20]
                             const float* __restrict__ fc_b,
                             float* __restrict__ out)           // [B]
{
    const int b = blockIdx.x * blockDim.x + threadIdx.x;
    if (b >= B_TOTAL) return;

    float in4[20];
    const __half* p = l3out + (size_t)(T_TOTAL - 1) * (B_TOTAL * 20) + (size_t)b * 20;
#pragma unroll
    for (int i = 0; i < 20; ++i) in4[i] = __half2float(p[i]);

    float z = fc_b[0];
#pragma unroll
    for (int k = 0; k < 10; ++k) z += fc_w[k] * hf4[b * 10 + k];

#pragma unroll
    for (int k = 0; k < 10; ++k) {
        float gi = b_ih[k]      + b_hh[k];
        float gg = b_ih[20 + k] + b_hh[20 + k];
        float go = b_ih[30 + k] + b_hh[30 + k];
#pragma unroll
        for (int i = 0; i < 20; ++i) {
            const float xi = in4[i];
            gi += w_ih[k * 20 + i]        * xi;
            gg += w_ih[(20 + k) * 20 + i] * xi;
            go += w_ih[(30 + k) * 20 + i] * xi;
        }
        const float cc = sigm_(gi) * tanh_(gg);
        const float hb = sigm_(go) * tanh_(cc);
        z += fc_w[10 + k] * hb;
    }
    out[b] = sigm_(z);
}

extern "C" void kernel_launch(void* const* d_in, const int* in_sizes, int n_in,
                              void* d_out, int out_size, void* d_ws, size_t ws_size,
                              hipStream_t stream) {
    const float* x = (const float*)d_in[0];
    auto W = [&](int li, int dr, int k) -> const float* {
        return (const float*)d_in[1 + (li - 1) * 8 + dr * 4 + k];
    };
    const float* fc_w = (const float*)d_in[33];
    const float* fc_b = (const float*)d_in[34];
    float* out = (float*)d_out;

    // ws: buf0 [T][B][40] f16 (80MB), buf1 [T][B][40] f16 (80MB), hf4 [B][10] f32
    __half* buf0 = (__half*)d_ws;
    __half* buf1 = buf0 + (size_t)T_TOTAL * B_TOTAL * 40;
    float* hf4 = (float*)(buf1 + (size_t)T_TOTAL * B_TOTAL * 40);

    // Layer 1: DIN=16 (x + lag), H=20 -> buf0 [T][B][40]
    lstm_scan<16, 20, true, true><<<dim3(342, 2, 1), 64, 0, stream>>>(
        x, nullptr,
        W(1,0,0), W(1,0,1), W(1,0,2), W(1,0,3),
        W(1,1,0), W(1,1,1), W(1,1,2), W(1,1,3),
        buf0, nullptr);

    // Layer 2: DIN=40, H=20 -> buf1 [T][B][40]
    lstm_scan<40, 20, false, true><<<dim3(342, 2, 1), 64, 0, stream>>>(
        nullptr, buf0,
        W(2,0,0), W(2,0,1), W(2,0,2), W(2,0,3),
        W(2,1,0), W(2,1,1), W(2,1,2), W(2,1,3),
        buf1, nullptr);

    // Layer 3: DIN=40, H=10 -> buf0 [T][B][20]
    lstm_scan<40, 10, false, true><<<dim3(171, 2, 1), 64, 0, stream>>>(
        nullptr, buf1,
        W(3,0,0), W(3,0,1), W(3,0,2), W(3,0,3),
        W(3,1,0), W(3,1,1), W(3,1,2), W(3,1,3),
        buf0, nullptr);

    // Layer 4 forward only: DIN=20, H=10 -> hf4 [B][10]
    lstm_scan<20, 10, false, false><<<dim3(171, 1, 1), 64, 0, stream>>>(
        nullptr, buf0,
        W(4,0,0), W(4,0,1), W(4,0,2), W(4,0,3),
        W(4,0,0), W(4,0,1), W(4,0,2), W(4,0,3), // dir=1 never launched
        nullptr, hf4);

    // L4 backward single step + FC + sigmoid
    final_kernel<<<dim3(4, 1, 1), 256, 0, stream>>>(
        buf0, hf4, W(4,1,0), W(4,1,2), W(4,1,3), fc_w, fc_b, out);
}

// Round 4
// 1730.966 us; speedup vs baseline: 2.0690x; 1.0161x over previous
//
#include <hip/hip_runtime.h>
#include <hip/hip_fp16.h>
#include <stdint.h>

#define B_TOTAL 1024
#define T_TOTAL 1024
#define LOG2E 1.44269504088896f

typedef _Float16 f16x2 __attribute__((ext_vector_type(2)));

__device__ __forceinline__ float dot2acc(uint32_t xw, f16x2 w, float acc) {
#if __has_builtin(__builtin_amdgcn_fdot2)
    return __builtin_amdgcn_fdot2(__builtin_bit_cast(f16x2, xw), w, acc, false);
#else
    f16x2 xv = __builtin_bit_cast(f16x2, xw);
    return acc + (float)xv.x * (float)w.x + (float)xv.y * (float)w.y;
#endif
}

__device__ __forceinline__ uint32_t packf2(float a, float b) {
    f16x2 t;
    t.x = (_Float16)a;
    t.y = (_Float16)b;
    return __builtin_bit_cast(uint32_t, t);
}

__device__ __forceinline__ float sigm_(float z) {
    float e = __builtin_amdgcn_exp2f(-LOG2E * z);
    return __builtin_amdgcn_rcpf(1.0f + e);
}
__device__ __forceinline__ float tanh_(float z) {
    float e = __builtin_amdgcn_exp2f((2.0f * LOG2E) * z);
    float r = __builtin_amdgcn_rcpf(1.0f + e);
    return __builtin_fmaf(-2.0f, r, 1.0f);
}

__device__ __forceinline__ void wavebar() {
#if __has_builtin(__builtin_amdgcn_wave_barrier)
    __builtin_amdgcn_wave_barrier();
#endif
}

// Lane = (batch-group g, hidden unit j). Each lane computes ALL 4 gates for
// unit j: no gate exchange, no __syncthreads. Groups fit in ONE wave
// (3x H=20 or 6x H=10), so the h broadcast is wave-lockstep LDS.
// Weights live in VGPRs (f16x2). Input prefetched 4 deep (quad buffer).
// __launch_bounds__(64, 1): ~1 wave/SIMD anyway (684 blocks), so let the
// allocator keep the full ~240-reg live set resident — round-3's 92-reg cap
// spilled weights to scratch (WRITE_SIZE showed +48 MiB of spill traffic).
template <int DIN, int H, bool LAYER1, bool STORE_ALL>
__global__ void __launch_bounds__(64, 1) lstm_scan(
    const float* __restrict__ x,              // LAYER1: [B][T][8] f32
    const __half* __restrict__ inbuf,         // layers>1: [T][B][DIN] f16
    const float* __restrict__ wihf, const float* __restrict__ whhf,
    const float* __restrict__ bihf, const float* __restrict__ bhhf,
    const float* __restrict__ wihb, const float* __restrict__ whhb,
    const float* __restrict__ bihb, const float* __restrict__ bhhb,
    __half* __restrict__ outbuf,              // STORE_ALL: [T][B][2H] f16
    float* __restrict__ lasth)                // !STORE_ALL: [B][H] f32
{
    constexpr int GPW   = 64 / H;     // batch groups per wave (3 or 6)
    constexpr int ND    = DIN / 2;    // input dwords (f16 pairs)
    constexpr int NH    = H / 2;      // h dwords
    constexpr int HS_DW = (H == 20) ? 12 : 8;  // padded LDS row (16B aligned)

    const int dir  = blockIdx.y;
    const int lane = threadIdx.x;
    const int g    = lane / H;
    const int j    = lane - g * H;
    const int b    = blockIdx.x * GPW + g;
    const bool valid = (g < GPW) && (b < B_TOTAL);
    const int bs   = valid ? b : (B_TOTAL - 1);

    const float* w_ih = dir ? wihb : wihf;
    const float* w_hh = dir ? whhb : whhf;
    const float* b_ih = dir ? bihb : bihf;
    const float* b_hh = dir ? bhhb : bhhf;

    __shared__ uint32_t hsm[GPW + 1][HS_DW];

    // ---- weights for all 4 gates of unit j -> registers (f16 pairs) ----
    f16x2 wih2[4][ND];
    f16x2 whh2[4][NH];
    float bias[4];
#pragma unroll
    for (int q = 0; q < 4; ++q) {
        const int r = q * H + j;
#pragma unroll
        for (int d = 0; d < ND; ++d) {
            f16x2 t;
            t.x = (_Float16)w_ih[r * DIN + 2 * d];
            t.y = (_Float16)w_ih[r * DIN + 2 * d + 1];
            wih2[q][d] = t;
        }
#pragma unroll
        for (int k = 0; k < NH; ++k) {
            f16x2 t;
            t.x = (_Float16)w_hh[r * H + 2 * k];
            t.y = (_Float16)w_hh[r * H + 2 * k + 1];
            whh2[q][k] = t;
        }
        bias[q] = b_ih[r] + b_hh[r];
    }

    const int tstep = dir ? -1 : 1;
    int tt = dir ? (T_TOTAL - 1) : 0;

    // output pointer (store guarded by `valid`)
    __half* op = nullptr;
    ptrdiff_t opstep = 0;
    if constexpr (STORE_ALL) {
        op = outbuf + (size_t)tt * (B_TOTAL * 2 * H) + (size_t)bs * (2 * H) + dir * H + j;
        opstep = (ptrdiff_t)tstep * (B_TOTAL * 2 * H);
    }

    float c = 0.0f;
    float hlast = 0.0f;               // final-step h (for !STORE_ALL)
    ((__half*)&hsm[g][0])[j] = __float2half(0.0f);
    wavebar();

    // shared tail: h-dots, activations, state update, h broadcast, store
    auto tail = [&](const uint32_t* hd, float a0, float a1, float a2, float a3) {
#pragma unroll
        for (int k = 0; k < NH; ++k) {
            a0 = dot2acc(hd[k], whh2[0][k], a0);
            a1 = dot2acc(hd[k], whh2[1][k], a1);
            a2 = dot2acc(hd[k], whh2[2][k], a2);
            a3 = dot2acc(hd[k], whh2[3][k], a3);
        }
        const float iv = sigm_(a0);
        const float fv = sigm_(a1);
        const float gv = tanh_(a2);
        const float ov = sigm_(a3);
        c = __builtin_fmaf(fv, c, iv * gv);
        const float h = ov * tanh_(c);
        ((__half*)&hsm[g][0])[j] = __float2half(h);
        wavebar();
        if constexpr (STORE_ALL) {
            if (valid) *op = __float2half(h);
            op += opstep;
        } else {
            hlast = h;
        }
        tt += tstep;
    };

    if constexpr (LAYER1) {
        const float* xrow = x + (size_t)bs * (T_TOTAL * 8);
        uint32_t xcur[4], xlag[4];
        {
            const float4* p = (const float4*)(xrow + (size_t)tt * 8);
            float4 u0 = p[0], u1 = p[1];
            xcur[0] = packf2(u0.x, u0.y); xcur[1] = packf2(u0.z, u0.w);
            xcur[2] = packf2(u1.x, u1.y); xcur[3] = packf2(u1.z, u1.w);
            if (dir) {
                const float4* q = (const float4*)(xrow + (size_t)(tt - 1) * 8);
                float4 v0 = q[0], v1 = q[1];
                xlag[0] = packf2(v0.x, v0.y); xlag[1] = packf2(v0.z, v0.w);
                xlag[2] = packf2(v1.x, v1.y); xlag[3] = packf2(v1.z, v1.w);
            } else {
#pragma unroll
                for (int d = 0; d < 4; ++d) xlag[d] = 0u;
            }
        }

        for (int t = 0; t < T_TOTAL; ++t) {
            uint32_t hd[NH];
#pragma unroll
            for (int k = 0; k < NH; ++k) hd[k] = hsm[g][k];

            float a0 = bias[0], a1 = bias[1], a2 = bias[2], a3 = bias[3];
#pragma unroll
            for (int d = 0; d < 4; ++d) {
                a0 = dot2acc(xcur[d], wih2[0][d], a0);
                a1 = dot2acc(xcur[d], wih2[1][d], a1);
                a2 = dot2acc(xcur[d], wih2[2][d], a2);
                a3 = dot2acc(xcur[d], wih2[3][d], a3);
            }
#pragma unroll
            for (int d = 0; d < 4; ++d) {
                a0 = dot2acc(xlag[d], wih2[0][4 + d], a0);
                a1 = dot2acc(xlag[d], wih2[1][4 + d], a1);
                a2 = dot2acc(xlag[d], wih2[2][4 + d], a2);
                a3 = dot2acc(xlag[d], wih2[3][4 + d], a3);
            }

            // prefetch next step's fresh row
            const int li = dir ? (tt - 2) : (tt + 1);
            const bool ld = (li >= 0) && (li < T_TOTAL);
            float4 n0 = {0, 0, 0, 0}, n1 = {0, 0, 0, 0};
            if (ld) {
                const float4* p = (const float4*)(xrow + (size_t)li * 8);
                n0 = p[0];
                n1 = p[1];
            }

            tail(hd, a0, a1, a2, a3);

            uint32_t np[4] = {packf2(n0.x, n0.y), packf2(n0.z, n0.w),
                              packf2(n1.x, n1.y), packf2(n1.z, n1.w)};
            if (dir == 0) {
#pragma unroll
                for (int d = 0; d < 4; ++d) { xlag[d] = xcur[d]; xcur[d] = np[d]; }
            } else {
#pragma unroll
                for (int d = 0; d < 4; ++d) {
                    xcur[d] = xlag[d];
                    xlag[d] = ld ? np[d] : 0u;
                }
            }
        }
    } else {
        const ptrdiff_t ipstep = (ptrdiff_t)tstep * (B_TOTAL * ND);
        const uint32_t* ip = (const uint32_t*)inbuf + (size_t)tt * (B_TOTAL * ND) + (size_t)bs * ND;

        uint32_t xb[4][ND];
#pragma unroll
        for (int s = 0; s < 3; ++s) {
#pragma unroll
            for (int d = 0; d < ND; ++d) xb[s][d] = ip[d];
            ip += ipstep;
        }

        auto step = [&](const uint32_t* xc, uint32_t* xn, bool pf) {
            uint32_t hd[NH];
#pragma unroll
            for (int k = 0; k < NH; ++k) hd[k] = hsm[g][k];

            float a0 = bias[0], a1 = bias[1], a2 = bias[2], a3 = bias[3];
#pragma unroll
            for (int d = 0; d < ND; ++d) {
                a0 = dot2acc(xc[d], wih2[0][d], a0);
                a1 = dot2acc(xc[d], wih2[1][d], a1);
                a2 = dot2acc(xc[d], wih2[2][d], a2);
                a3 = dot2acc(xc[d], wih2[3][d], a3);
            }
            if (pf) {
#pragma unroll
                for (int d = 0; d < ND; ++d) xn[d] = ip[d];
                ip += ipstep;
            }
            tail(hd, a0, a1, a2, a3);
        };

        for (int t = 0; t < T_TOTAL; t += 4) {
            step(xb[0], xb[3], t + 3 < T_TOTAL);
            step(xb[1], xb[0], t + 4 < T_TOTAL);
            step(xb[2], xb[1], t + 5 < T_TOTAL);
            step(xb[3], xb[2], t + 6 < T_TOTAL);
        }
    }

    if constexpr (!STORE_ALL) {
        if (valid) lasth[b * H + j] = hlast;
    }
}

// L4 backward needed only at t=T-1 (single step from zero state) + FC + sigmoid.
__global__ void final_kernel(const __half* __restrict__ l3out,  // [T][B][20] f16
                             const float* __restrict__ hf4,     // [B][10]
                             const float* __restrict__ w_ih,    // w4b_ih [40][20]
                             const float* __restrict__ b_ih,
                             const float* __restrict__ b_hh,
                             const float* __restrict__ fc_w,    // [20]
                             const float* __restrict__ fc_b,
                             float* __restrict__ out)           // [B]
{
    const int b = blockIdx.x * blockDim.x + threadIdx.x;
    if (b >= B_TOTAL) return;

    float in4[20];
    const __half* p = l3out + (size_t)(T_TOTAL - 1) * (B_TOTAL * 20) + (size_t)b * 20;
#pragma unroll
    for (int i = 0; i < 20; ++i) in4[i] = __half2float(p[i]);

    float z = fc_b[0];
#pragma unroll
    for (int k = 0; k < 10; ++k) z += fc_w[k] * hf4[b * 10 + k];

#pragma unroll
    for (int k = 0; k < 10; ++k) {
        float gi = b_ih[k]      + b_hh[k];
        float gg = b_ih[20 + k] + b_hh[20 + k];
        float go = b_ih[30 + k] + b_hh[30 + k];
#pragma unroll
        for (int i = 0; i < 20; ++i) {
            const float xi = in4[i];
            gi += w_ih[k * 20 + i]        * xi;
            gg += w_ih[(20 + k) * 20 + i] * xi;
            go += w_ih[(30 + k) * 20 + i] * xi;
        }
        const float cc = sigm_(gi) * tanh_(gg);
        const float hb = sigm_(go) * tanh_(cc);
        z += fc_w[10 + k] * hb;
    }
    out[b] = sigm_(z);
}

extern "C" void kernel_launch(void* const* d_in, const int* in_sizes, int n_in,
                              void* d_out, int out_size, void* d_ws, size_t ws_size,
                              hipStream_t stream) {
    const float* x = (const float*)d_in[0];
    auto W = [&](int li, int dr, int k) -> const float* {
        return (const float*)d_in[1 + (li - 1) * 8 + dr * 4 + k];
    };
    const float* fc_w = (const float*)d_in[33];
    const float* fc_b = (const float*)d_in[34];
    float* out = (float*)d_out;

    // ws: buf0 [T][B][40] f16 (80MB), buf1 [T][B][40] f16 (80MB), hf4 [B][10] f32
    __half* buf0 = (__half*)d_ws;
    __half* buf1 = buf0 + (size_t)T_TOTAL * B_TOTAL * 40;
    float* hf4 = (float*)(buf1 + (size_t)T_TOTAL * B_TOTAL * 40);

    // Layer 1: DIN=16 (x + lag), H=20 -> buf0 [T][B][40]
    lstm_scan<16, 20, true, true><<<dim3(342, 2, 1), 64, 0, stream>>>(
        x, nullptr,
        W(1,0,0), W(1,0,1), W(1,0,2), W(1,0,3),
        W(1,1,0), W(1,1,1), W(1,1,2), W(1,1,3),
        buf0, nullptr);

    // Layer 2: DIN=40, H=20 -> buf1 [T][B][40]
    lstm_scan<40, 20, false, true><<<dim3(342, 2, 1), 64, 0, stream>>>(
        nullptr, buf0,
        W(2,0,0), W(2,0,1), W(2,0,2), W(2,0,3),
        W(2,1,0), W(2,1,1), W(2,1,2), W(2,1,3),
        buf1, nullptr);

    // Layer 3: DIN=40, H=10 -> buf0 [T][B][20]
    lstm_scan<40, 10, false, true><<<dim3(171, 2, 1), 64, 0, stream>>>(
        nullptr, buf1,
        W(3,0,0), W(3,0,1), W(3,0,2), W(3,0,3),
        W(3,1,0), W(3,1,1), W(3,1,2), W(3,1,3),
        buf0, nullptr);

    // Layer 4 forward only: DIN=20, H=10 -> hf4 [B][10]
    lstm_scan<20, 10, false, false><<<dim3(171, 1, 1), 64, 0, stream>>>(
        nullptr, buf0,
        W(4,0,0), W(4,0,1), W(4,0,2), W(4,0,3),
        W(4,0,0), W(4,0,1), W(4,0,2), W(4,0,3), // dir=1 never launched
        nullptr, hf4);

    // L4 backward single step + FC + sigmoid
    final_kernel<<<dim3(4, 1, 1), 256, 0, stream>>>(
        buf0, hf4, W(4,1,0), W(4,1,2), W(4,1,3), fc_w, fc_b, out);
}